// Round 1
// baseline (563.801 us; speedup 1.0000x reference)
//
#include <hip/hip_runtime.h>
#include <hip/hip_bf16.h>
#include <cstdint>

#define BQ 8
#define NQ 2048
#define FQ 128

typedef __attribute__((ext_vector_type(8))) short short8;
typedef __attribute__((ext_vector_type(4))) float f32x4;

__device__ __forceinline__ unsigned short f2bf(float f) {
    union { float f; unsigned int u; } c; c.f = f;
    unsigned int u = c.u;
    u = (u + 0x7FFFu + ((u >> 16) & 1u)) >> 16;   // RNE
    return (unsigned short)u;
}

// ---------------- Kernel 1: row L2-normalize, fp32 -> bf16 ----------------
__global__ __launch_bounds__(256) void k_rownorm(const float* __restrict__ h,
                                                 unsigned short* __restrict__ xn) {
    int wave = threadIdx.x >> 6;
    int lane = threadIdx.x & 63;
    int row = blockIdx.x * 4 + wave;          // one wave per row
    const float* hr = h + (size_t)row * FQ;
    float e0 = hr[lane], e1 = hr[lane + 64];
    float s = e0 * e0 + e1 * e1;
    #pragma unroll
    for (int m = 32; m; m >>= 1) s += __shfl_xor(s, m, 64);
    float inv = 1.0f / fmaxf(sqrtf(s), 1e-8f);
    unsigned short* xr = xn + (size_t)row * FQ;
    xr[lane]      = f2bf(e0 * inv);
    xr[lane + 64] = f2bf(e1 * inv);
}

// ---- Kernel 2: S = xn @ xn^T (MFMA), threshold > t, write adj bf16, row-sums d ----
// grid: B * N/64 blocks, 4 waves; wave owns 16 rows x all 2048 cols, K=128
__global__ __launch_bounds__(256) void k_adj(const unsigned short* __restrict__ xn,
                                             unsigned short* __restrict__ adj,
                                             float* __restrict__ d, float t) {
    int blk  = blockIdx.x;
    int bb   = blk >> 5;                       // batch
    int rt   = blk & 31;                       // row tile within batch
    int wave = threadIdx.x >> 6;
    int lane = threadIdx.x & 63;
    int rowb = rt * 64 + wave * 16;
    int g = lane >> 4, c = lane & 15;

    const unsigned short* xb = xn + (size_t)bb * NQ * FQ;
    short8 a[4];
    #pragma unroll
    for (int ks = 0; ks < 4; ++ks)
        a[ks] = *(const short8*)(xb + (size_t)(rowb + c) * FQ + ks * 32 + g * 8);

    float dloc[4] = {0.f, 0.f, 0.f, 0.f};
    unsigned short* adjb = adj + (size_t)bb * NQ * NQ;

    for (int ct = 0; ct < NQ / 16; ++ct) {
        int colb = ct * 16;
        f32x4 acc = {0.f, 0.f, 0.f, 0.f};
        #pragma unroll
        for (int ks = 0; ks < 4; ++ks) {
            short8 bfr = *(const short8*)(xb + (size_t)(colb + c) * FQ + ks * 32 + g * 8);
            acc = __builtin_amdgcn_mfma_f32_16x16x32_bf16(a[ks], bfr, acc, 0, 0, 0);
        }
        #pragma unroll
        for (int r = 0; r < 4; ++r) {
            float v = acc[r];
            v = (v > t) ? v : 0.0f;            // strict threshold, matches reference
            dloc[r] += v;
            adjb[(size_t)(rowb + g * 4 + r) * NQ + colb + c] = f2bf(v);
        }
    }
    // reduce row sums across the 16 lanes of each 4-row group (same g)
    #pragma unroll
    for (int r = 0; r < 4; ++r) {
        float s = dloc[r];
        s += __shfl_xor(s, 1, 64);
        s += __shfl_xor(s, 2, 64);
        s += __shfl_xor(s, 4, 64);
        s += __shfl_xor(s, 8, 64);
        dloc[r] = s;
    }
    if (c == 0) {
        #pragma unroll
        for (int r = 0; r < 4; ++r)
            d[(size_t)bb * NQ + rowb + g * 4 + r] = dloc[r];
    }
}

// ---- Kernel 3: isq = 1/sqrt(d);  hsT[b][f][m] = bf16(h[b][m][f] * isq[m]) ----
__global__ __launch_bounds__(256) void k_prep(const float* __restrict__ h,
                                              const float* __restrict__ d,
                                              float* __restrict__ isq,
                                              unsigned short* __restrict__ hsT) {
    __shared__ float tile[32][129];
    __shared__ float iv[32];
    int r0 = blockIdx.x * 32;                  // global row base (b*N + m0)
    int bb = r0 >> 11;
    int m0 = r0 & (NQ - 1);
    int tid = threadIdx.x;
    if (tid < 32) {
        float v = 1.0f / sqrtf(d[r0 + tid]);
        iv[tid] = v;
        isq[r0 + tid] = v;
    }
    #pragma unroll
    for (int it = 0; it < 16; ++it) {
        int idx = tid + it * 256;
        int mi = idx >> 7, f = idx & 127;
        tile[mi][f] = h[(size_t)(r0 + mi) * FQ + f];
    }
    __syncthreads();
    unsigned short* hb = hsT + (size_t)bb * FQ * NQ;
    #pragma unroll
    for (int it = 0; it < 16; ++it) {
        int idx = tid + it * 256;
        int f = idx >> 5, mi = idx & 31;
        hb[(size_t)f * NQ + m0 + mi] = f2bf(tile[mi][f] * iv[mi]);
    }
}

// ---- Kernel 4: h_out[n][f] = isq[n] * sum_m adj[n][m] * hsT[f][m]  (MFMA, K=2048) ----
__global__ __launch_bounds__(256) void k_gemm2(const unsigned short* __restrict__ adj,
                                               const unsigned short* __restrict__ hsT,
                                               const float* __restrict__ isq,
                                               float* __restrict__ hout) {
    int blk  = blockIdx.x;
    int bb   = blk >> 5;
    int rt   = blk & 31;
    int wave = threadIdx.x >> 6;
    int lane = threadIdx.x & 63;
    int rowb = rt * 64 + wave * 16;
    int g = lane >> 4, c = lane & 15;

    const unsigned short* adjr = adj + (size_t)bb * NQ * NQ + (size_t)(rowb + c) * NQ;
    const unsigned short* hb   = hsT + (size_t)bb * FQ * NQ;

    f32x4 acc[8];
    #pragma unroll
    for (int i = 0; i < 8; ++i) acc[i] = (f32x4){0.f, 0.f, 0.f, 0.f};

    for (int kk = 0; kk < NQ / 32; ++kk) {
        short8 afr = *(const short8*)(adjr + kk * 32 + g * 8);
        #pragma unroll
        for (int ct = 0; ct < 8; ++ct) {
            short8 bfr = *(const short8*)(hb + (size_t)(ct * 16 + c) * NQ + kk * 32 + g * 8);
            acc[ct] = __builtin_amdgcn_mfma_f32_16x16x32_bf16(afr, bfr, acc[ct], 0, 0, 0);
        }
    }
    float is[4];
    #pragma unroll
    for (int r = 0; r < 4; ++r) is[r] = isq[(size_t)bb * NQ + rowb + g * 4 + r];
    float* ho = hout + (size_t)bb * NQ * FQ;
    #pragma unroll
    for (int ct = 0; ct < 8; ++ct)
        #pragma unroll
        for (int r = 0; r < 4; ++r)
            ho[(size_t)(rowb + g * 4 + r) * FQ + ct * 16 + c] = acc[ct][r] * is[r];
}

// ---- Kernel 5: out = (h3 + x) @ W   (fp32 vector, tiny) ----
__global__ __launch_bounds__(256) void k_out(const float* __restrict__ h3,
                                             const float* __restrict__ x,
                                             const float* __restrict__ W,
                                             float* __restrict__ out) {
    __shared__ float hx[8][128];
    int r0 = blockIdx.x * 8;
    int tid = threadIdx.x;
    #pragma unroll
    for (int it = 0; it < 4; ++it) {
        int idx = tid + it * 256;
        int ri = idx >> 7, f = idx & 127;
        size_t gi = (size_t)(r0 + ri) * FQ + f;
        hx[ri][f] = h3[gi] + x[gi];
    }
    __syncthreads();
    int o = tid & 127, half = tid >> 7;
    float acc[4] = {0.f, 0.f, 0.f, 0.f};
    for (int f = 0; f < 128; ++f) {
        float wv = W[f * 128 + o];
        #pragma unroll
        for (int j = 0; j < 4; ++j)
            acc[j] += hx[half * 4 + j][f] * wv;
    }
    #pragma unroll
    for (int j = 0; j < 4; ++j)
        out[(size_t)(r0 + half * 4 + j) * FQ + o] = acc[j];
}

extern "C" void kernel_launch(void* const* d_in, const int* in_sizes, int n_in,
                              void* d_out, int out_size, void* d_ws, size_t ws_size,
                              hipStream_t stream) {
    const float* x = (const float*)d_in[0];
    const float* W = (const float*)d_in[1];
    float* out = (float*)d_out;
    char* ws = (char*)d_ws;

    const size_t oADJ = 0;
    const size_t oHA  = oADJ + (size_t)BQ * NQ * NQ * 2;   // 67108864
    const size_t oHB  = oHA  + (size_t)BQ * NQ * FQ * 4;   // +8MB
    const size_t oXN  = oHB  + (size_t)BQ * NQ * FQ * 4;   // +8MB
    const size_t oHST = oXN  + (size_t)BQ * NQ * FQ * 2;   // +4MB
    const size_t oD   = oHST + (size_t)BQ * NQ * FQ * 2;   // +4MB
    const size_t oISQ = oD   + (size_t)BQ * NQ * 4;        // +64KB
    const size_t need = oISQ + (size_t)BQ * NQ * 4;        // ~88MB
    if (ws_size < need) return;   // workspace too small -> leaves poison (diagnostic)

    unsigned short* adj = (unsigned short*)(ws + oADJ);
    float* hA = (float*)(ws + oHA);
    float* hB = (float*)(ws + oHB);
    unsigned short* xn  = (unsigned short*)(ws + oXN);
    unsigned short* hsT = (unsigned short*)(ws + oHST);
    float* dv  = (float*)(ws + oD);
    float* isq = (float*)(ws + oISQ);

    const float ts[3] = {0.05f, 0.1f, 0.15f};
    const float* hin = x;
    float* houts[3] = {hA, hB, hA};

    for (int i = 0; i < 3; ++i) {
        k_rownorm<<<BQ * NQ / 4,  256, 0, stream>>>(hin, xn);
        k_adj    <<<BQ * NQ / 64, 256, 0, stream>>>(xn, adj, dv, ts[i]);
        k_prep   <<<BQ * NQ / 32, 256, 0, stream>>>(hin, dv, isq, hsT);
        k_gemm2  <<<BQ * NQ / 64, 256, 0, stream>>>(adj, hsT, isq, houts[i]);
        hin = houts[i];
    }
    k_out<<<BQ * NQ / 8, 256, 0, stream>>>(hA, x, W, out);
}

// Round 2
// 386.173 us; speedup vs baseline: 1.4600x; 1.4600x over previous
//
#include <hip/hip_runtime.h>
#include <hip/hip_bf16.h>
#include <cstdint>

#define BQ 8
#define NQ 2048
#define FQ 128

typedef __attribute__((ext_vector_type(8))) short short8;
typedef __attribute__((ext_vector_type(4))) float f32x4;
typedef __attribute__((ext_vector_type(4))) unsigned short us4;

__device__ __forceinline__ unsigned short f2bf(float f) {
    union { float f; unsigned int u; } c; c.f = f;
    unsigned int u = c.u;
    u = (u + 0x7FFFu + ((u >> 16) & 1u)) >> 16;   // RNE
    return (unsigned short)u;
}

// ---------------- Kernel 1a: row L2-normalize (iter 0, reads x) ----------------
__global__ __launch_bounds__(256) void k_rownorm(const float* __restrict__ h,
                                                 unsigned short* __restrict__ xn) {
    int wave = threadIdx.x >> 6;
    int lane = threadIdx.x & 63;
    size_t row = (size_t)blockIdx.x * 4 + wave;
    const float* hr = h + row * FQ;
    float e0 = hr[lane], e1 = hr[lane + 64];
    float s = e0 * e0 + e1 * e1;
    #pragma unroll
    for (int m = 32; m; m >>= 1) s += __shfl_xor(s, m, 64);
    float inv = 1.0f / fmaxf(sqrtf(s), 1e-8f);
    unsigned short* xr = xn + row * FQ;
    xr[lane]      = f2bf(e0 * inv);
    xr[lane + 64] = f2bf(e1 * inv);
}

// ------- Kernel 1b: reduce K-split partials -> h, then normalize -> xn -------
template<int KC>
__global__ __launch_bounds__(256) void k_rownorm4(const float* __restrict__ hp,
                                                  float* __restrict__ hout,
                                                  unsigned short* __restrict__ xn) {
    const size_t CS = (size_t)BQ * NQ * FQ;
    int wave = threadIdx.x >> 6;
    int lane = threadIdx.x & 63;
    size_t row = (size_t)blockIdx.x * 4 + wave;
    size_t o0 = row * FQ + lane, o1 = o0 + 64;
    float e0 = 0.f, e1 = 0.f;
    #pragma unroll
    for (int k = 0; k < KC; ++k) { e0 += hp[k * CS + o0]; e1 += hp[k * CS + o1]; }
    hout[o0] = e0; hout[o1] = e1;
    float s = e0 * e0 + e1 * e1;
    #pragma unroll
    for (int m = 32; m; m >>= 1) s += __shfl_xor(s, m, 64);
    float inv = 1.0f / fmaxf(sqrtf(s), 1e-8f);
    xn[o0] = f2bf(e0 * inv);
    xn[o1] = f2bf(e1 * inv);
}

// ---- Kernel 2: S = xn@xn^T, threshold, store tile TRANSPOSED (S symmetric),
//      per-(block-col, batch) partial row sums into dpart. 128x128 tile/block. ----
__global__ __launch_bounds__(256) void k_adj(const unsigned short* __restrict__ xn,
                                             unsigned short* __restrict__ adj,
                                             float* __restrict__ dpart, float t) {
    int blk = blockIdx.x;
    int bb  = blk >> 8;                        // batch
    int ij  = blk & 255;
    int I   = ij >> 4, J = ij & 15;            // 128-row / 128-col tile
    int wid = threadIdx.x >> 6, lane = threadIdx.x & 63;
    int wr = wid >> 1, wc = wid & 1;
    int g = lane >> 4, c = lane & 15;

    const unsigned short* xb = xn + (size_t)bb * NQ * FQ;
    int rowb = I * 128 + wr * 64;
    int colb = J * 128 + wc * 64;

    short8 a[4][4];
    #pragma unroll
    for (int mi = 0; mi < 4; ++mi)
        #pragma unroll
        for (int ks = 0; ks < 4; ++ks)
            a[mi][ks] = *(const short8*)(xb + (size_t)(rowb + mi * 16 + c) * FQ + ks * 32 + g * 8);

    f32x4 acc[4][4];
    #pragma unroll
    for (int mi = 0; mi < 4; ++mi)
        #pragma unroll
        for (int ni = 0; ni < 4; ++ni) acc[mi][ni] = (f32x4){0.f, 0.f, 0.f, 0.f};

    #pragma unroll
    for (int ni = 0; ni < 4; ++ni) {
        short8 b[4];
        #pragma unroll
        for (int ks = 0; ks < 4; ++ks)
            b[ks] = *(const short8*)(xb + (size_t)(colb + ni * 16 + c) * FQ + ks * 32 + g * 8);
        #pragma unroll
        for (int mi = 0; mi < 4; ++mi)
            #pragma unroll
            for (int ks = 0; ks < 4; ++ks)
                acc[mi][ni] = __builtin_amdgcn_mfma_f32_16x16x32_bf16(a[mi][ks], b[ks], acc[mi][ni], 0, 0, 0);
    }

    // epilogue: threshold, partial row sums, transposed 8B stores
    unsigned short* adjb = adj + (size_t)bb * NQ * NQ;
    __shared__ float dsm[2][128];
    float dl[4][4];
    #pragma unroll
    for (int mi = 0; mi < 4; ++mi)
        #pragma unroll
        for (int r = 0; r < 4; ++r) dl[mi][r] = 0.f;

    #pragma unroll
    for (int mi = 0; mi < 4; ++mi)
        #pragma unroll
        for (int ni = 0; ni < 4; ++ni) {
            f32x4 v = acc[mi][ni];
            us4 u;
            #pragma unroll
            for (int r = 0; r < 4; ++r) {
                float x = v[r];
                x = (x > t) ? x : 0.0f;        // strict threshold
                dl[mi][r] += x;
                u[r] = f2bf(x);
            }
            // tile is symmetric under global relabeling: store transposed at mirror slot
            *(us4*)(adjb + (size_t)(colb + ni * 16 + c) * NQ + rowb + mi * 16 + g * 4) = u;
        }

    #pragma unroll
    for (int mi = 0; mi < 4; ++mi)
        #pragma unroll
        for (int r = 0; r < 4; ++r) {
            float s = dl[mi][r];
            s += __shfl_xor(s, 1, 64);
            s += __shfl_xor(s, 2, 64);
            s += __shfl_xor(s, 4, 64);
            s += __shfl_xor(s, 8, 64);
            dl[mi][r] = s;
        }
    if (c == 0) {
        #pragma unroll
        for (int mi = 0; mi < 4; ++mi)
            #pragma unroll
            for (int r = 0; r < 4; ++r)
                dsm[wc][wr * 64 + mi * 16 + g * 4 + r] = dl[mi][r];
    }
    __syncthreads();
    int tid = threadIdx.x;
    if (tid < 128)
        dpart[((size_t)J * 8 + bb) * NQ + I * 128 + tid] = dsm[0][tid] + dsm[1][tid];
}

// ---- Kernel 3: isq = 1/sqrt(sum_J dpart);  hsT[b][f][m] = bf16(h[b][m][f]*isq[m]) ----
__global__ __launch_bounds__(256) void k_prep(const float* __restrict__ h,
                                              const float* __restrict__ dpart,
                                              float* __restrict__ isq,
                                              unsigned short* __restrict__ hsT) {
    __shared__ float tile[32][129];
    __shared__ float iv[32];
    int r0 = blockIdx.x * 32;                  // global row base (b*N + m0)
    int bb = r0 >> 11;
    int m0 = r0 & (NQ - 1);
    int tid = threadIdx.x;
    if (tid < 32) {
        float s = 0.f;
        #pragma unroll
        for (int j = 0; j < 16; ++j)
            s += dpart[((size_t)j * 8 + bb) * NQ + m0 + tid];
        float v = 1.0f / sqrtf(s);
        iv[tid] = v;
        isq[r0 + tid] = v;
    }
    #pragma unroll
    for (int it = 0; it < 16; ++it) {
        int idx = tid + it * 256;
        int mi = idx >> 7, f = idx & 127;
        tile[mi][f] = h[(size_t)(r0 + mi) * FQ + f];
    }
    __syncthreads();
    unsigned short* hb = hsT + (size_t)bb * FQ * NQ;
    #pragma unroll
    for (int it = 0; it < 16; ++it) {
        int idx = tid + it * 256;
        int f = idx >> 5, mi = idx & 31;
        hb[(size_t)f * NQ + m0 + mi] = f2bf(tile[mi][f] * iv[mi]);
    }
}

// ---- Kernel 4: hpart[kc] = isq[n] * (adj[:, Kchunk] @ hsT[:, Kchunk]^T) ----
template<int KC>
__global__ __launch_bounds__(256) void k_gemm2(const unsigned short* __restrict__ adj,
                                               const unsigned short* __restrict__ hsT,
                                               const float* __restrict__ isq,
                                               float* __restrict__ hpart) {
    constexpr int KE = NQ / KC;                // K elems per chunk
    constexpr int KS = KE / 32;                // k-steps
    const size_t CS = (size_t)BQ * NQ * FQ;
    int blk = blockIdx.x;
    int kc = blk % KC;
    int rt = (blk / KC) & 31;
    int bb = blk / (KC * 32);
    int wid = threadIdx.x >> 6, lane = threadIdx.x & 63;
    int g = lane >> 4, c = lane & 15;
    int row0 = rt * 64 + wid * 16;

    const unsigned short* adjr = adj + (size_t)bb * NQ * NQ + (size_t)(row0 + c) * NQ + kc * KE;
    const unsigned short* hb   = hsT + (size_t)bb * FQ * NQ + kc * KE;

    f32x4 acc[8];
    #pragma unroll
    for (int i = 0; i < 8; ++i) acc[i] = (f32x4){0.f, 0.f, 0.f, 0.f};

    for (int kk = 0; kk < KS; ++kk) {
        short8 afr = *(const short8*)(adjr + kk * 32 + g * 8);
        #pragma unroll
        for (int ct = 0; ct < 8; ++ct) {
            short8 bfr = *(const short8*)(hb + (size_t)(ct * 16 + c) * NQ + kk * 32 + g * 8);
            acc[ct] = __builtin_amdgcn_mfma_f32_16x16x32_bf16(afr, bfr, acc[ct], 0, 0, 0);
        }
    }
    float is[4];
    #pragma unroll
    for (int r = 0; r < 4; ++r) is[r] = isq[(size_t)bb * NQ + row0 + g * 4 + r];
    float* hp = hpart + (size_t)kc * CS + (size_t)bb * NQ * FQ;
    #pragma unroll
    for (int ct = 0; ct < 8; ++ct)
        #pragma unroll
        for (int r = 0; r < 4; ++r)
            hp[(size_t)(row0 + g * 4 + r) * FQ + ct * 16 + c] = acc[ct][r] * is[r];
}

// ---- Kernel 5: out = (sum_kc hpart + x) @ W ----
template<int KC>
__global__ __launch_bounds__(256) void k_out4(const float* __restrict__ hp,
                                              const float* __restrict__ x,
                                              const float* __restrict__ W,
                                              float* __restrict__ out) {
    const size_t CS = (size_t)BQ * NQ * FQ;
    __shared__ float hx[8][128];
    int r0 = blockIdx.x * 8;
    int tid = threadIdx.x;
    #pragma unroll
    for (int it = 0; it < 4; ++it) {
        int idx = tid + it * 256;
        int ri = idx >> 7, f = idx & 127;
        size_t gi = (size_t)(r0 + ri) * FQ + f;
        float s = x[gi];
        #pragma unroll
        for (int k = 0; k < KC; ++k) s += hp[k * CS + gi];
        hx[ri][f] = s;
    }
    __syncthreads();
    int o = tid & 127, half = tid >> 7;
    float acc[4] = {0.f, 0.f, 0.f, 0.f};
    for (int f = 0; f < 128; ++f) {
        float wv = W[f * 128 + o];
        #pragma unroll
        for (int j = 0; j < 4; ++j)
            acc[j] += hx[half * 4 + j][f] * wv;
    }
    #pragma unroll
    for (int j = 0; j < 4; ++j)
        out[(size_t)(r0 + half * 4 + j) * FQ + o] = acc[j];
}

template<int KC>
static void run_all(const float* x, const float* W, float* out,
                    unsigned short* adj, unsigned short* xn, unsigned short* hsT,
                    float* dpart, float* isq, float* h, float* hpart,
                    hipStream_t stream) {
    const float ts[3] = {0.05f, 0.1f, 0.15f};
    for (int i = 0; i < 3; ++i) {
        if (i == 0) k_rownorm<<<BQ * NQ / 4, 256, 0, stream>>>(x, xn);
        else        k_rownorm4<KC><<<BQ * NQ / 4, 256, 0, stream>>>(hpart, h, xn);
        k_adj<<<BQ * 256, 256, 0, stream>>>(xn, adj, dpart, ts[i]);
        k_prep<<<BQ * NQ / 32, 256, 0, stream>>>(i == 0 ? x : h, dpart, isq, hsT);
        k_gemm2<KC><<<BQ * 32 * KC, 256, 0, stream>>>(adj, hsT, isq, hpart);
    }
    k_out4<KC><<<BQ * NQ / 8, 256, 0, stream>>>(hpart, x, W, out);
}

extern "C" void kernel_launch(void* const* d_in, const int* in_sizes, int n_in,
                              void* d_out, int out_size, void* d_ws, size_t ws_size,
                              hipStream_t stream) {
    const float* x = (const float*)d_in[0];
    const float* W = (const float*)d_in[1];
    float* out = (float*)d_out;
    char* ws = (char*)d_ws;

    const size_t CS   = (size_t)BQ * NQ * FQ;                 // 2M elems
    const size_t oADJ = 0;
    const size_t oXN  = oADJ + (size_t)BQ * NQ * NQ * 2;      // 64 MiB
    const size_t oHST = oXN  + CS * 2;                        // +4 MiB
    const size_t oD   = oHST + CS * 2;                        // +4 MiB
    const size_t oISQ = oD   + (size_t)16 * BQ * NQ * 4;      // +1 MiB
    const size_t oH   = oISQ + (size_t)BQ * NQ * 4;           // +64 KiB
    const size_t oHP  = oH   + CS * 4;                        // +8 MiB
    const size_t need1 = oHP + 1 * CS * 4;
    const size_t need2 = oHP + 2 * CS * 4;
    const size_t need4 = oHP + 4 * CS * 4;

    unsigned short* adj = (unsigned short*)(ws + oADJ);
    unsigned short* xn  = (unsigned short*)(ws + oXN);
    unsigned short* hsT = (unsigned short*)(ws + oHST);
    float* dpart = (float*)(ws + oD);
    float* isq   = (float*)(ws + oISQ);
    float* h     = (float*)(ws + oH);
    float* hpart = (float*)(ws + oHP);

    if (ws_size >= need4)
        run_all<4>(x, W, out, adj, xn, hsT, dpart, isq, h, hpart, stream);
    else if (ws_size >= need2)
        run_all<2>(x, W, out, adj, xn, hsT, dpart, isq, h, hpart, stream);
    else if (ws_size >= need1)
        run_all<1>(x, W, out, adj, xn, hsT, dpart, isq, h, hpart, stream);
    // else: workspace too small (diagnostic — output stays poisoned)
}

// Round 3
// 206.790 us; speedup vs baseline: 2.7264x; 1.8675x over previous
//
#include <hip/hip_runtime.h>
#include <hip/hip_bf16.h>
#include <cstdint>

#define BQ 8
#define NQ 2048
#define FQ 128
#define NG (NQ * 16)            // adjF n-group stride (elems)

typedef __attribute__((ext_vector_type(8))) short short8;
typedef __attribute__((ext_vector_type(4))) float f32x4;
typedef __attribute__((ext_vector_type(4))) unsigned short us4;
typedef __attribute__((ext_vector_type(8))) unsigned short us8;

__device__ __forceinline__ unsigned short f2bf(float f) {
    union { float f; unsigned int u; } c; c.f = f;
    unsigned int u = c.u;
    u = (u + 0x7FFFu + ((u >> 16) & 1u)) >> 16;   // RNE
    return (unsigned short)u;
}

// Fragment layouts (per batch):
//   xnF : [n/16][k/8][n%16][k%8]   addr = (n>>4)*2048 + (k>>3)*128 + (n&15)*8 + (k&7)
//   adjF: [n/16][m/8][n%16][m%8]   addr = (n>>4)*NG   + (m>>3)*128 + (n&15)*8 + (m&7)
//   hsF : [m/8][f][m%8]            addr = (m>>3)*1024 + f*8 + (m&7)

// ---- Kernel 1a: row L2-normalize x -> xnF (16 rows/block) ----
__global__ __launch_bounds__(256) void k_rownorm(const float* __restrict__ h,
                                                 unsigned short* __restrict__ xnF) {
    int t = threadIdx.x;
    int rl = t >> 4;                 // local row 0..15
    int j  = t & 15;                 // k-chunk
    size_t row = (size_t)blockIdx.x * 16 + rl;
    const float* hr = h + row * FQ + j * 8;
    float v[8];
    #pragma unroll
    for (int e = 0; e < 8; ++e) v[e] = hr[e];
    float s = 0.f;
    #pragma unroll
    for (int e = 0; e < 8; ++e) s += v[e] * v[e];
    s += __shfl_xor(s, 1, 64);
    s += __shfl_xor(s, 2, 64);
    s += __shfl_xor(s, 4, 64);
    s += __shfl_xor(s, 8, 64);
    float inv = 1.0f / fmaxf(sqrtf(s), 1e-8f);
    us8 u;
    #pragma unroll
    for (int e = 0; e < 8; ++e) u[e] = f2bf(v[e] * inv);
    *(us8*)(xnF + (size_t)blockIdx.x * 2048 + j * 128 + rl * 8) = u;
}

// ---- Kernel 1b: reduce K-split partials -> h, normalize -> xnF ----
template<int KC>
__global__ __launch_bounds__(256) void k_rownorm4(const float* __restrict__ hp,
                                                  float* __restrict__ hout,
                                                  unsigned short* __restrict__ xnF) {
    const size_t CS = (size_t)BQ * NQ * FQ;
    int t = threadIdx.x;
    int rl = t >> 4, j = t & 15;
    size_t row = (size_t)blockIdx.x * 16 + rl;
    size_t o = row * FQ + j * 8;
    float v[8];
    #pragma unroll
    for (int e = 0; e < 8; ++e) {
        float s = 0.f;
        #pragma unroll
        for (int k = 0; k < KC; ++k) s += hp[k * CS + o + e];
        v[e] = s;
    }
    #pragma unroll
    for (int e = 0; e < 8; ++e) hout[o + e] = v[e];
    float s = 0.f;
    #pragma unroll
    for (int e = 0; e < 8; ++e) s += v[e] * v[e];
    s += __shfl_xor(s, 1, 64);
    s += __shfl_xor(s, 2, 64);
    s += __shfl_xor(s, 4, 64);
    s += __shfl_xor(s, 8, 64);
    float inv = 1.0f / fmaxf(sqrtf(s), 1e-8f);
    us8 u;
    #pragma unroll
    for (int e = 0; e < 8; ++e) u[e] = f2bf(v[e] * inv);
    *(us8*)(xnF + (size_t)blockIdx.x * 2048 + j * 128 + rl * 8) = u;
}

// ---- Kernel 2: S = xn@xn^T, threshold, store transposed tile into adjF,
//      partial row sums -> dpart. 128x128 tile per block. ----
__global__ __launch_bounds__(256) void k_adj(const unsigned short* __restrict__ xnF,
                                             unsigned short* __restrict__ adjF,
                                             float* __restrict__ dpart, float t) {
    int blk = blockIdx.x;
    int bb  = blk >> 8;
    int ij  = blk & 255;
    int I   = ij >> 4, J = ij & 15;
    int wid = threadIdx.x >> 6, lane = threadIdx.x & 63;
    int wr = wid >> 1, wc = wid & 1;
    int g = lane >> 4, c = lane & 15;

    const unsigned short* xb = xnF + (size_t)bb * NQ * FQ;
    int rowb = I * 128 + wr * 64;
    int colb = J * 128 + wc * 64;

    short8 a[4][4];
    #pragma unroll
    for (int mi = 0; mi < 4; ++mi)
        #pragma unroll
        for (int ks = 0; ks < 4; ++ks)
            a[mi][ks] = *(const short8*)(xb + (size_t)((rowb >> 4) + mi) * 2048 + (ks * 4 + g) * 128 + c * 8);

    f32x4 acc[4][4];
    #pragma unroll
    for (int mi = 0; mi < 4; ++mi)
        #pragma unroll
        for (int ni = 0; ni < 4; ++ni) acc[mi][ni] = (f32x4){0.f, 0.f, 0.f, 0.f};

    #pragma unroll
    for (int ni = 0; ni < 4; ++ni) {
        short8 b[4];
        #pragma unroll
        for (int ks = 0; ks < 4; ++ks)
            b[ks] = *(const short8*)(xb + (size_t)((colb >> 4) + ni) * 2048 + (ks * 4 + g) * 128 + c * 8);
        #pragma unroll
        for (int mi = 0; mi < 4; ++mi)
            #pragma unroll
            for (int ks = 0; ks < 4; ++ks)
                acc[mi][ni] = __builtin_amdgcn_mfma_f32_16x16x32_bf16(a[mi][ks], b[ks], acc[mi][ni], 0, 0, 0);
    }

    unsigned short* adjb = adjF + (size_t)bb * NQ * NQ;
    __shared__ float dsm[2][128];
    float dl[4][4];
    #pragma unroll
    for (int mi = 0; mi < 4; ++mi)
        #pragma unroll
        for (int r = 0; r < 4; ++r) dl[mi][r] = 0.f;

    #pragma unroll
    for (int mi = 0; mi < 4; ++mi)
        #pragma unroll
        for (int ni = 0; ni < 4; ++ni) {
            f32x4 v = acc[mi][ni];
            us4 u;
            #pragma unroll
            for (int r = 0; r < 4; ++r) {
                float x = v[r];
                x = (x > t) ? x : 0.0f;       // strict threshold
                dl[mi][r] += x;
                u[r] = f2bf(x);
            }
            // symmetric: element (row=rowb+mi*16+g*4+r, col=colb+ni*16+c) stored at
            // mirror (n=col, m=row) in fragment layout
            *(us4*)(adjb + (size_t)((colb >> 4) + ni) * NG
                         + (size_t)((rowb >> 3) + mi * 2 + (g >> 1)) * 128
                         + c * 8 + (g & 1) * 4) = u;
        }

    #pragma unroll
    for (int mi = 0; mi < 4; ++mi)
        #pragma unroll
        for (int r = 0; r < 4; ++r) {
            float s = dl[mi][r];
            s += __shfl_xor(s, 1, 64);
            s += __shfl_xor(s, 2, 64);
            s += __shfl_xor(s, 4, 64);
            s += __shfl_xor(s, 8, 64);
            dl[mi][r] = s;
        }
    if (c == 0) {
        #pragma unroll
        for (int mi = 0; mi < 4; ++mi)
            #pragma unroll
            for (int r = 0; r < 4; ++r)
                dsm[wc][wr * 64 + mi * 16 + g * 4 + r] = dl[mi][r];
    }
    __syncthreads();
    int tid = threadIdx.x;
    if (tid < 128)
        dpart[((size_t)J * 8 + bb) * NQ + I * 128 + tid] = dsm[0][tid] + dsm[1][tid];
}

// ---- Kernel 3: isq = 1/sqrt(sum dpart); hsF[m/8][f][m%8] = bf16(h[m][f]*isq[m]) ----
__global__ __launch_bounds__(256) void k_prep(const float* __restrict__ h,
                                              const float* __restrict__ dpart,
                                              float* __restrict__ isq,
                                              unsigned short* __restrict__ hsF) {
    __shared__ float tile[32][129];
    __shared__ float iv[32];
    int r0 = blockIdx.x * 32;
    int bb = r0 >> 11;
    int m0 = r0 & (NQ - 1);
    int tid = threadIdx.x;
    if (tid < 32) {
        float s = 0.f;
        #pragma unroll
        for (int j = 0; j < 16; ++j)
            s += dpart[((size_t)j * 8 + bb) * NQ + m0 + tid];
        float v = 1.0f / sqrtf(s);
        iv[tid] = v;
        isq[r0 + tid] = v;
    }
    #pragma unroll
    for (int it = 0; it < 16; ++it) {
        int idx = tid + it * 256;
        int mi = idx >> 7, f = idx & 127;
        tile[mi][f] = h[(size_t)(r0 + mi) * FQ + f];
    }
    __syncthreads();
    unsigned short* hb = hsF + (size_t)bb * NQ * FQ;
    #pragma unroll
    for (int it = 0; it < 2; ++it) {
        int p = tid + it * 256;
        int f = p & 127, mc = p >> 7;          // mc 0..3
        us8 u;
        #pragma unroll
        for (int e = 0; e < 8; ++e)
            u[e] = f2bf(tile[mc * 8 + e][f] * iv[mc * 8 + e]);
        *(us8*)(hb + (size_t)((m0 >> 3) + mc) * 1024 + f * 8) = u;
    }
}

// ---- Kernel 4: hpart[kc] = isq[n] * (adjF[:,Kchunk] @ hsF[Kchunk,:]) ----
template<int KC>
__global__ __launch_bounds__(256) void k_gemm2(const unsigned short* __restrict__ adjF,
                                               const unsigned short* __restrict__ hsF,
                                               const float* __restrict__ isq,
                                               float* __restrict__ hpart) {
    constexpr int KE = NQ / KC;
    constexpr int KS = KE / 32;
    const size_t CS = (size_t)BQ * NQ * FQ;
    int blk = blockIdx.x;
    int kc = blk % KC;
    int rt = (blk / KC) & 31;
    int bb = blk / (KC * 32);
    int wid = threadIdx.x >> 6, lane = threadIdx.x & 63;
    int g = lane >> 4, c = lane & 15;
    int row0 = rt * 64 + wid * 16;

    const unsigned short* adjr = adjF + (size_t)bb * NQ * NQ + (size_t)(row0 >> 4) * NG
                                      + (size_t)((kc * KE) >> 3) * 128;
    const unsigned short* hb   = hsF + (size_t)bb * NQ * FQ + (size_t)((kc * KE) >> 3) * 1024;

    f32x4 acc[8];
    #pragma unroll
    for (int i = 0; i < 8; ++i) acc[i] = (f32x4){0.f, 0.f, 0.f, 0.f};

    #pragma unroll 2
    for (int kk = 0; kk < KS; ++kk) {
        short8 afr = *(const short8*)(adjr + (size_t)(kk * 4 + g) * 128 + c * 8);
        #pragma unroll
        for (int ct = 0; ct < 8; ++ct) {
            short8 bfr = *(const short8*)(hb + (size_t)(kk * 4 + g) * 1024 + ct * 128 + c * 8);
            acc[ct] = __builtin_amdgcn_mfma_f32_16x16x32_bf16(afr, bfr, acc[ct], 0, 0, 0);
        }
    }
    float is[4];
    #pragma unroll
    for (int r = 0; r < 4; ++r) is[r] = isq[(size_t)bb * NQ + row0 + g * 4 + r];
    float* hp = hpart + (size_t)kc * CS + (size_t)bb * NQ * FQ;
    #pragma unroll
    for (int ct = 0; ct < 8; ++ct)
        #pragma unroll
        for (int r = 0; r < 4; ++r)
            hp[(size_t)(row0 + g * 4 + r) * FQ + ct * 16 + c] = acc[ct][r] * is[r];
}

// ---- Kernel 5: out = (sum_kc hpart + x) @ W ----
template<int KC>
__global__ __launch_bounds__(256) void k_out4(const float* __restrict__ hp,
                                              const float* __restrict__ x,
                                              const float* __restrict__ W,
                                              float* __restrict__ out) {
    const size_t CS = (size_t)BQ * NQ * FQ;
    __shared__ float hx[8][128];
    int r0 = blockIdx.x * 8;
    int tid = threadIdx.x;
    #pragma unroll
    for (int it = 0; it < 4; ++it) {
        int idx = tid + it * 256;
        int ri = idx >> 7, f = idx & 127;
        size_t gi = (size_t)(r0 + ri) * FQ + f;
        float s = x[gi];
        #pragma unroll
        for (int k = 0; k < KC; ++k) s += hp[k * CS + gi];
        hx[ri][f] = s;
    }
    __syncthreads();
    int o = tid & 127, half = tid >> 7;
    float acc[4] = {0.f, 0.f, 0.f, 0.f};
    for (int f = 0; f < 128; ++f) {
        float wv = W[f * 128 + o];
        #pragma unroll
        for (int j = 0; j < 4; ++j)
            acc[j] += hx[half * 4 + j][f] * wv;
    }
    #pragma unroll
    for (int j = 0; j < 4; ++j)
        out[(size_t)(r0 + half * 4 + j) * FQ + o] = acc[j];
}

template<int KC>
static void run_all(const float* x, const float* W, float* out,
                    unsigned short* adjF, unsigned short* xnF, unsigned short* hsF,
                    float* dpart, float* isq, float* h, float* hpart,
                    hipStream_t stream) {
    const float ts[3] = {0.05f, 0.1f, 0.15f};
    for (int i = 0; i < 3; ++i) {
        if (i == 0) k_rownorm<<<BQ * NQ / 16, 256, 0, stream>>>(x, xnF);
        else        k_rownorm4<KC><<<BQ * NQ / 16, 256, 0, stream>>>(hpart, h, xnF);
        k_adj<<<BQ * 256, 256, 0, stream>>>(xnF, adjF, dpart, ts[i]);
        k_prep<<<BQ * NQ / 32, 256, 0, stream>>>(i == 0 ? x : h, dpart, isq, hsF);
        k_gemm2<KC><<<BQ * 32 * KC, 256, 0, stream>>>(adjF, hsF, isq, hpart);
    }
    k_out4<KC><<<BQ * NQ / 8, 256, 0, stream>>>(hpart, x, W, out);
}

extern "C" void kernel_launch(void* const* d_in, const int* in_sizes, int n_in,
                              void* d_out, int out_size, void* d_ws, size_t ws_size,
                              hipStream_t stream) {
    const float* x = (const float*)d_in[0];
    const float* W = (const float*)d_in[1];
    float* out = (float*)d_out;
    char* ws = (char*)d_ws;

    const size_t CS   = (size_t)BQ * NQ * FQ;
    const size_t oADJ = 0;
    const size_t oXN  = oADJ + (size_t)BQ * NQ * NQ * 2;      // 64 MiB
    const size_t oHST = oXN  + CS * 2;                        // +4 MiB
    const size_t oD   = oHST + CS * 2;                        // +4 MiB
    const size_t oISQ = oD   + (size_t)16 * BQ * NQ * 4;      // +1 MiB
    const size_t oH   = oISQ + (size_t)BQ * NQ * 4;           // +64 KiB
    const size_t oHP  = oH   + CS * 4;                        // +8 MiB
    const size_t need1 = oHP + 1 * CS * 4;
    const size_t need2 = oHP + 2 * CS * 4;
    const size_t need4 = oHP + 4 * CS * 4;

    unsigned short* adjF = (unsigned short*)(ws + oADJ);
    unsigned short* xnF  = (unsigned short*)(ws + oXN);
    unsigned short* hsF  = (unsigned short*)(ws + oHST);
    float* dpart = (float*)(ws + oD);
    float* isq   = (float*)(ws + oISQ);
    float* h     = (float*)(ws + oH);
    float* hpart = (float*)(ws + oHP);

    if (ws_size >= need4)
        run_all<4>(x, W, out, adjF, xnF, hsF, dpart, isq, h, hpart, stream);
    else if (ws_size >= need2)
        run_all<2>(x, W, out, adjF, xnF, hsF, dpart, isq, h, hpart, stream);
    else if (ws_size >= need1)
        run_all<1>(x, W, out, adjF, xnF, hsF, dpart, isq, h, hpart, stream);
    // else: workspace too small (diagnostic — output stays poisoned)
}

// Round 4
// 183.560 us; speedup vs baseline: 3.0715x; 1.1266x over previous
//
#include <hip/hip_runtime.h>
#include <hip/hip_bf16.h>
#include <cstdint>

#define BQ 8
#define NQ 2048
#define FQ 128
#define NG (NQ * 16)            // adjF n-group stride (elems)

typedef __attribute__((ext_vector_type(8))) short short8;
typedef __attribute__((ext_vector_type(4))) float f32x4;
typedef __attribute__((ext_vector_type(4))) unsigned short us4;
typedef __attribute__((ext_vector_type(8))) unsigned short us8;
typedef __attribute__((ext_vector_type(2))) unsigned int u32x2;

__device__ __forceinline__ unsigned short f2bf(float f) {
    union { float f; unsigned int u; } c; c.f = f;
    unsigned int u = c.u;
    u = (u + 0x7FFFu + ((u >> 16) & 1u)) >> 16;   // RNE
    return (unsigned short)u;
}

// packed f32x2 -> bf16x2 (RNE), hardware cvt
__device__ __forceinline__ unsigned int cvtpk(float lo, float hi) {
    unsigned int r;
    asm("v_cvt_pk_bf16_f32 %0, %1, %2" : "=v"(r) : "v"(lo), "v"(hi));
    return r;
}

// Fragment layouts (per batch):
//   xnF : [n/16][k/8][n%16][k%8]   addr = (n>>4)*2048 + (k>>3)*128 + (n&15)*8 + (k&7)
//   adjF: [n/16][m/8][n%16][m%8]   addr = (n>>4)*NG   + (m>>3)*128 + (n&15)*8 + (m&7)
//   hsF : [m/8][f][m%8]            addr = (m>>3)*1024 + f*8 + (m&7)

// ---- Kernel 1a: row L2-normalize x -> xnF (16 rows/block) ----
__global__ __launch_bounds__(256) void k_rownorm(const float* __restrict__ h,
                                                 unsigned short* __restrict__ xnF) {
    int t = threadIdx.x;
    int rl = t >> 4;                 // local row 0..15
    int j  = t & 15;                 // k-chunk
    size_t row = (size_t)blockIdx.x * 16 + rl;
    const float* hr = h + row * FQ + j * 8;
    float v[8];
    #pragma unroll
    for (int e = 0; e < 8; ++e) v[e] = hr[e];
    float s = 0.f;
    #pragma unroll
    for (int e = 0; e < 8; ++e) s += v[e] * v[e];
    s += __shfl_xor(s, 1, 64);
    s += __shfl_xor(s, 2, 64);
    s += __shfl_xor(s, 4, 64);
    s += __shfl_xor(s, 8, 64);
    float inv = 1.0f / fmaxf(sqrtf(s), 1e-8f);
    us8 u;
    #pragma unroll
    for (int e = 0; e < 8; ++e) u[e] = f2bf(v[e] * inv);
    *(us8*)(xnF + (size_t)blockIdx.x * 2048 + j * 128 + rl * 8) = u;
}

// ---- Kernel 1b: reduce K-split partials -> h, normalize -> xnF ----
template<int KC>
__global__ __launch_bounds__(256) void k_rownorm4(const float* __restrict__ hp,
                                                  float* __restrict__ hout,
                                                  unsigned short* __restrict__ xnF) {
    const size_t CS = (size_t)BQ * NQ * FQ;
    int t = threadIdx.x;
    int rl = t >> 4, j = t & 15;
    size_t row = (size_t)blockIdx.x * 16 + rl;
    size_t o = row * FQ + j * 8;
    float v[8];
    #pragma unroll
    for (int e = 0; e < 8; ++e) {
        float s = 0.f;
        #pragma unroll
        for (int k = 0; k < KC; ++k) s += hp[k * CS + o + e];
        v[e] = s;
    }
    #pragma unroll
    for (int e = 0; e < 8; ++e) hout[o + e] = v[e];
    float s = 0.f;
    #pragma unroll
    for (int e = 0; e < 8; ++e) s += v[e] * v[e];
    s += __shfl_xor(s, 1, 64);
    s += __shfl_xor(s, 2, 64);
    s += __shfl_xor(s, 4, 64);
    s += __shfl_xor(s, 8, 64);
    float inv = 1.0f / fmaxf(sqrtf(s), 1e-8f);
    us8 u;
    #pragma unroll
    for (int e = 0; e < 8; ++e) u[e] = f2bf(v[e] * inv);
    *(us8*)(xnF + (size_t)blockIdx.x * 2048 + j * 128 + rl * 8) = u;
}

// ---- Kernel 2: S = xn@xn^T, threshold, store transposed tile into adjF,
//      partial row sums -> dpart. 128x128 tile per block, XCD-swizzled. ----
__global__ __launch_bounds__(256) void k_adj(const unsigned short* __restrict__ xnF,
                                             unsigned short* __restrict__ adjF,
                                             float* __restrict__ dpart, float t) {
    // XCD swizzle: grid 2048 (divisible by 8); blocks with same I-tile -> same XCD
    int bid = blockIdx.x;
    int blk = (bid & 7) * (int)(gridDim.x >> 3) + (bid >> 3);
    int bb  = blk >> 8;
    int ij  = blk & 255;
    int I   = ij >> 4, J = ij & 15;
    int wid = threadIdx.x >> 6, lane = threadIdx.x & 63;
    int wr = wid >> 1, wc = wid & 1;
    int g = lane >> 4, c = lane & 15;

    const unsigned short* xb = xnF + (size_t)bb * NQ * FQ;
    int rowb = I * 128 + wr * 64;
    int colb = J * 128 + wc * 64;

    short8 a[4][4];
    #pragma unroll
    for (int mi = 0; mi < 4; ++mi)
        #pragma unroll
        for (int ks = 0; ks < 4; ++ks)
            a[mi][ks] = *(const short8*)(xb + (size_t)((rowb >> 4) + mi) * 2048 + (ks * 4 + g) * 128 + c * 8);

    f32x4 acc[4][4];
    #pragma unroll
    for (int mi = 0; mi < 4; ++mi)
        #pragma unroll
        for (int ni = 0; ni < 4; ++ni) acc[mi][ni] = (f32x4){0.f, 0.f, 0.f, 0.f};

    #pragma unroll
    for (int ni = 0; ni < 4; ++ni) {
        short8 b[4];
        #pragma unroll
        for (int ks = 0; ks < 4; ++ks)
            b[ks] = *(const short8*)(xb + (size_t)((colb >> 4) + ni) * 2048 + (ks * 4 + g) * 128 + c * 8);
        #pragma unroll
        for (int mi = 0; mi < 4; ++mi)
            #pragma unroll
            for (int ks = 0; ks < 4; ++ks)
                acc[mi][ni] = __builtin_amdgcn_mfma_f32_16x16x32_bf16(a[mi][ks], b[ks], acc[mi][ni], 0, 0, 0);
    }

    unsigned short* adjb = adjF + (size_t)bb * NQ * NQ;
    __shared__ float dsm[2][128];
    float dl[4][4];
    #pragma unroll
    for (int mi = 0; mi < 4; ++mi)
        #pragma unroll
        for (int r = 0; r < 4; ++r) dl[mi][r] = 0.f;

    #pragma unroll
    for (int mi = 0; mi < 4; ++mi)
        #pragma unroll
        for (int ni = 0; ni < 4; ++ni) {
            f32x4 v = acc[mi][ni];
            float x0 = (v[0] > t) ? v[0] : 0.0f;   // strict threshold in f32
            float x1 = (v[1] > t) ? v[1] : 0.0f;
            float x2 = (v[2] > t) ? v[2] : 0.0f;
            float x3 = (v[3] > t) ? v[3] : 0.0f;
            dl[mi][0] += x0; dl[mi][1] += x1; dl[mi][2] += x2; dl[mi][3] += x3;
            u32x2 u;
            u[0] = cvtpk(x0, x1);
            u[1] = cvtpk(x2, x3);
            // symmetric: element (row=rowb+mi*16+g*4+r, col=colb+ni*16+c) stored at
            // mirror (n=col, m=row) in fragment layout
            *(u32x2*)(adjb + (size_t)((colb >> 4) + ni) * NG
                           + (size_t)((rowb >> 3) + mi * 2 + (g >> 1)) * 128
                           + c * 8 + (g & 1) * 4) = u;
        }

    #pragma unroll
    for (int mi = 0; mi < 4; ++mi)
        #pragma unroll
        for (int r = 0; r < 4; ++r) {
            float s = dl[mi][r];
            s += __shfl_xor(s, 1, 64);
            s += __shfl_xor(s, 2, 64);
            s += __shfl_xor(s, 4, 64);
            s += __shfl_xor(s, 8, 64);
            dl[mi][r] = s;
        }
    if (c == 0) {
        #pragma unroll
        for (int mi = 0; mi < 4; ++mi)
            #pragma unroll
            for (int r = 0; r < 4; ++r)
                dsm[wc][wr * 64 + mi * 16 + g * 4 + r] = dl[mi][r];
    }
    __syncthreads();
    int tid = threadIdx.x;
    if (tid < 128)
        dpart[((size_t)J * 8 + bb) * NQ + I * 128 + tid] = dsm[0][tid] + dsm[1][tid];
}

// ---- Kernel 3: isq = 1/sqrt(sum dpart); hsF[m/8][f][m%8] = bf16(h[m][f]*isq[m]) ----
__global__ __launch_bounds__(256) void k_prep(const float* __restrict__ h,
                                              const float* __restrict__ dpart,
                                              float* __restrict__ isq,
                                              unsigned short* __restrict__ hsF) {
    __shared__ float tile[32][129];
    __shared__ float iv[32];
    int r0 = blockIdx.x * 32;
    int bb = r0 >> 11;
    int m0 = r0 & (NQ - 1);
    int tid = threadIdx.x;
    if (tid < 32) {
        float s = 0.f;
        #pragma unroll
        for (int j = 0; j < 16; ++j)
            s += dpart[((size_t)j * 8 + bb) * NQ + m0 + tid];
        float v = 1.0f / sqrtf(s);
        iv[tid] = v;
        isq[r0 + tid] = v;
    }
    #pragma unroll
    for (int it = 0; it < 16; ++it) {
        int idx = tid + it * 256;
        int mi = idx >> 7, f = idx & 127;
        tile[mi][f] = h[(size_t)(r0 + mi) * FQ + f];
    }
    __syncthreads();
    unsigned short* hb = hsF + (size_t)bb * NQ * FQ;
    #pragma unroll
    for (int it = 0; it < 2; ++it) {
        int p = tid + it * 256;
        int f = p & 127, mc = p >> 7;          // mc 0..3
        us8 u;
        #pragma unroll
        for (int e = 0; e < 8; ++e)
            u[e] = f2bf(tile[mc * 8 + e][f] * iv[mc * 8 + e]);
        *(us8*)(hb + (size_t)((m0 >> 3) + mc) * 1024 + f * 8) = u;
    }
}

// ---- Kernel 4: hpart[kc] = isq[n] * (adjF[:,Kchunk] @ hsF[Kchunk,:])
//      32 rows/wave, 128 rows/block, XCD-swizzled. ----
template<int KC>
__global__ __launch_bounds__(256, 1) void k_gemm2(const unsigned short* __restrict__ adjF,
                                                  const unsigned short* __restrict__ hsF,
                                                  const float* __restrict__ isq,
                                                  float* __restrict__ hpart) {
    constexpr int KE = NQ / KC;
    constexpr int KS = KE / 32;
    const size_t CS = (size_t)BQ * NQ * FQ;
    int bid = blockIdx.x;
    int lb = (bid & 7) * (int)(gridDim.x >> 3) + (bid >> 3);   // XCD swizzle
    int kc = lb % KC;
    int rt = (lb / KC) & 15;
    int bb = lb / (KC * 16);
    int wid = threadIdx.x >> 6, lane = threadIdx.x & 63;
    int g = lane >> 4, c = lane & 15;
    int row0 = rt * 128 + wid * 32;

    const unsigned short* adjr = adjF + (size_t)bb * NQ * NQ + (size_t)(row0 >> 4) * NG
                                      + (size_t)((kc * KE) >> 3) * 128;
    const unsigned short* hb   = hsF + (size_t)bb * NQ * FQ + (size_t)((kc * KE) >> 3) * 1024;

    f32x4 acc[2][8];
    #pragma unroll
    for (int mi = 0; mi < 2; ++mi)
        #pragma unroll
        for (int i = 0; i < 8; ++i) acc[mi][i] = (f32x4){0.f, 0.f, 0.f, 0.f};

    #pragma unroll 2
    for (int kk = 0; kk < KS; ++kk) {
        short8 a0 = *(const short8*)(adjr + (size_t)(kk * 4 + g) * 128 + c * 8);
        short8 a1 = *(const short8*)(adjr + NG + (size_t)(kk * 4 + g) * 128 + c * 8);
        #pragma unroll
        for (int ct = 0; ct < 8; ++ct) {
            short8 bfr = *(const short8*)(hb + (size_t)(kk * 4 + g) * 1024 + ct * 128 + c * 8);
            acc[0][ct] = __builtin_amdgcn_mfma_f32_16x16x32_bf16(a0, bfr, acc[0][ct], 0, 0, 0);
            acc[1][ct] = __builtin_amdgcn_mfma_f32_16x16x32_bf16(a1, bfr, acc[1][ct], 0, 0, 0);
        }
    }
    float* hp = hpart + (size_t)kc * CS + (size_t)bb * NQ * FQ;
    #pragma unroll
    for (int mi = 0; mi < 2; ++mi) {
        float is[4];
        #pragma unroll
        for (int r = 0; r < 4; ++r) is[r] = isq[(size_t)bb * NQ + row0 + mi * 16 + g * 4 + r];
        #pragma unroll
        for (int ct = 0; ct < 8; ++ct)
            #pragma unroll
            for (int r = 0; r < 4; ++r)
                hp[(size_t)(row0 + mi * 16 + g * 4 + r) * FQ + ct * 16 + c] = acc[mi][ct][r] * is[r];
    }
}

// ---- Kernel 5: out = (sum_kc hpart + x) @ W ----
template<int KC>
__global__ __launch_bounds__(256) void k_out4(const float* __restrict__ hp,
                                              const float* __restrict__ x,
                                              const float* __restrict__ W,
                                              float* __restrict__ out) {
    const size_t CS = (size_t)BQ * NQ * FQ;
    __shared__ float hx[8][128];
    int r0 = blockIdx.x * 8;
    int tid = threadIdx.x;
    #pragma unroll
    for (int it = 0; it < 4; ++it) {
        int idx = tid + it * 256;
        int ri = idx >> 7, f = idx & 127;
        size_t gi = (size_t)(r0 + ri) * FQ + f;
        float s = x[gi];
        #pragma unroll
        for (int k = 0; k < KC; ++k) s += hp[k * CS + gi];
        hx[ri][f] = s;
    }
    __syncthreads();
    int o = tid & 127, half = tid >> 7;
    float acc[4] = {0.f, 0.f, 0.f, 0.f};
    for (int f = 0; f < 128; ++f) {
        float wv = W[f * 128 + o];
        #pragma unroll
        for (int j = 0; j < 4; ++j)
            acc[j] += hx[half * 4 + j][f] * wv;
    }
    #pragma unroll
    for (int j = 0; j < 4; ++j)
        out[(size_t)(r0 + half * 4 + j) * FQ + o] = acc[j];
}

template<int KC>
static void run_all(const float* x, const float* W, float* out,
                    unsigned short* adjF, unsigned short* xnF, unsigned short* hsF,
                    float* dpart, float* isq, float* h, float* hpart,
                    hipStream_t stream) {
    const float ts[3] = {0.05f, 0.1f, 0.15f};
    for (int i = 0; i < 3; ++i) {
        if (i == 0) k_rownorm<<<BQ * NQ / 16, 256, 0, stream>>>(x, xnF);
        else        k_rownorm4<KC><<<BQ * NQ / 16, 256, 0, stream>>>(hpart, h, xnF);
        k_adj<<<BQ * 256, 256, 0, stream>>>(xnF, adjF, dpart, ts[i]);
        k_prep<<<BQ * NQ / 32, 256, 0, stream>>>(i == 0 ? x : h, dpart, isq, hsF);
        k_gemm2<KC><<<BQ * 16 * KC, 256, 0, stream>>>(adjF, hsF, isq, hpart);
    }
    k_out4<KC><<<BQ * NQ / 8, 256, 0, stream>>>(hpart, x, W, out);
}

extern "C" void kernel_launch(void* const* d_in, const int* in_sizes, int n_in,
                              void* d_out, int out_size, void* d_ws, size_t ws_size,
                              hipStream_t stream) {
    const float* x = (const float*)d_in[0];
    const float* W = (const float*)d_in[1];
    float* out = (float*)d_out;
    char* ws = (char*)d_ws;

    const size_t CS   = (size_t)BQ * NQ * FQ;
    const size_t oADJ = 0;
    const size_t oXN  = oADJ + (size_t)BQ * NQ * NQ * 2;      // 64 MiB
    const size_t oHST = oXN  + CS * 2;                        // +4 MiB
    const size_t oD   = oHST + CS * 2;                        // +4 MiB
    const size_t oISQ = oD   + (size_t)16 * BQ * NQ * 4;      // +1 MiB
    const size_t oH   = oISQ + (size_t)BQ * NQ * 4;           // +64 KiB
    const size_t oHP  = oH   + CS * 4;                        // +8 MiB
    const size_t need1 = oHP + 1 * CS * 4;
    const size_t need2 = oHP + 2 * CS * 4;

    unsigned short* adjF = (unsigned short*)(ws + oADJ);
    unsigned short* xnF  = (unsigned short*)(ws + oXN);
    unsigned short* hsF  = (unsigned short*)(ws + oHST);
    float* dpart = (float*)(ws + oD);
    float* isq   = (float*)(ws + oISQ);
    float* h     = (float*)(ws + oH);
    float* hpart = (float*)(ws + oHP);

    if (ws_size >= need2)
        run_all<2>(x, W, out, adjF, xnF, hsF, dpart, isq, h, hpart, stream);
    else if (ws_size >= need1)
        run_all<1>(x, W, out, adjF, xnF, hsF, dpart, isq, h, hpart, stream);
    // else: workspace too small (diagnostic — output stays poisoned)
}